// Round 2
// baseline (256.969 us; speedup 1.0000x reference)
//
#include <hip/hip_runtime.h>
#include <math.h>

#define L_SEQ 2048
#define V 512
#define NB 8
#define NROWS (NB * L_SEQ)          // 16384
#define NSPLIT 32
#define EPS 1e-10

// ---- workspace layout (bytes) ----
// p      : (NROWS+1) rows x V fp32   (row NROWS is a zero pad row)
// gpart  : NSPLIT x V x V fp32       (GEMM K-split partials, fully overwritten)
// m      : V fp32                    (third-position marginal, atomically accumulated)
// sc     : 4 doubles S1,T1,S2,T2     (atomically accumulated)
#define P_OFF   ((size_t)0)
#define GP_OFF  ((size_t)(NROWS + 1) * V * sizeof(float))          // 33,556,480
#define M_OFF   (GP_OFF + (size_t)NSPLIT * V * V * sizeof(float))  // 67,110,912
#define SC_OFF  (M_OFF + (size_t)V * sizeof(float))                // 67,112,960

// ------------------- softmax (nan_to_num + softmax over V) -------------------
__global__ __launch_bounds__(64) void softmax_k(const float* __restrict__ in,
                                                float* __restrict__ p) {
    int row = blockIdx.x;
    int t = threadIdx.x;
    const float* x = in + (size_t)row * V;
    float4 va = *(const float4*)(x + t * 4);
    float4 vb = *(const float4*)(x + 256 + t * 4);
    float v[8] = {va.x, va.y, va.z, va.w, vb.x, vb.y, vb.z, vb.w};
#pragma unroll
    for (int i = 0; i < 8; i++) {
        float xi = v[i];
        if (isnan(xi)) xi = 0.0f;
        else if (isinf(xi)) xi = xi > 0.0f ? 80.0f : -80.0f;
        v[i] = xi;
    }
    float mx = v[0];
#pragma unroll
    for (int i = 1; i < 8; i++) mx = fmaxf(mx, v[i]);
#pragma unroll
    for (int o = 32; o; o >>= 1) mx = fmaxf(mx, __shfl_xor(mx, o, 64));
    float e[8];
    float s = 0.0f;
#pragma unroll
    for (int i = 0; i < 8; i++) { e[i] = expf(v[i] - mx); s += e[i]; }
#pragma unroll
    for (int o = 32; o; o >>= 1) s += __shfl_xor(s, o, 64);
    float inv = 1.0f / s;
    float* out = p + (size_t)row * V;
    float4 oa = make_float4(e[0] * inv, e[1] * inv, e[2] * inv, e[3] * inv);
    float4 ob = make_float4(e[4] * inv, e[5] * inv, e[6] * inv, e[7] * inv);
    *(float4*)(out + t * 4) = oa;
    *(float4*)(out + 256 + t * 4) = ob;
}

// ------------------- column sums of p over rows with l >= 2 -------------------
__global__ __launch_bounds__(256) void colsum_k(const float* __restrict__ p,
                                                float* __restrict__ m) {
    int t = threadIdx.x;
    int r0 = blockIdx.x * 64;   // 256 blocks x 64 rows
    float a0 = 0.0f, a1 = 0.0f;
    for (int i = 0; i < 64; i++) {
        int r = r0 + i;
        if ((r & (L_SEQ - 1)) >= 2) {       // wave-uniform branch
            const float* pr = p + (size_t)r * V + 2 * t;
            float2 v = *(const float2*)pr;
            a0 += v.x;
            a1 += v.y;
        }
    }
    atomicAdd(&m[2 * t], a0);
    atomicAdd(&m[2 * t + 1], a1);
}

// ------------------- dense GEMM: gpart[s] = P[k0:k0+512]^T @ P[k0+1:k0+513] ---
// (no masking; boundary pairs are subtracted analytically in reduceg_k)
#define BK 16
__global__ __launch_bounds__(256) void gemm_k(const float* __restrict__ p,
                                              float* __restrict__ gp) {
    __shared__ float sA[BK][128];
    __shared__ float sB[BK][128];
    int tile = blockIdx.x & 15;       // 4x4 tiles of 128x128
    int split = blockIdx.x >> 4;      // 32 K-splits
    int ta = (tile >> 2) * 128;
    int tb = (tile & 3) * 128;
    int k0 = split * 512;
    int t = threadIdx.x;
    int tx = t & 15, ty = t >> 4;
    int srow = t >> 4;                // staging: 16 rows x 16 threads/row
    int scol = (t & 15) * 8;          // 8 floats per thread per tile

    float acc[8][8];
#pragma unroll
    for (int i = 0; i < 8; i++)
#pragma unroll
        for (int j = 0; j < 8; j++) acc[i][j] = 0.0f;

    for (int k = k0; k < k0 + 512; k += BK) {
        const float* pa = p + (size_t)(k + srow) * V + ta + scol;
        const float* pb = p + (size_t)(k + srow + 1) * V + tb + scol;
        float4 a0 = *(const float4*)pa;
        float4 a1 = *(const float4*)(pa + 4);
        float4 b0 = *(const float4*)pb;
        float4 b1 = *(const float4*)(pb + 4);
        __syncthreads();                        // previous iter's LDS reads done
        *(float4*)&sA[srow][scol] = a0;
        *(float4*)&sA[srow][scol + 4] = a1;
        *(float4*)&sB[srow][scol] = b0;
        *(float4*)&sB[srow][scol + 4] = b1;
        __syncthreads();
#pragma unroll
        for (int kk = 0; kk < BK; kk++) {
            float4 aLo = *(float4*)&sA[kk][ty * 4];
            float4 aHi = *(float4*)&sA[kk][ty * 4 + 64];
            float4 bLo = *(float4*)&sB[kk][tx * 4];
            float4 bHi = *(float4*)&sB[kk][tx * 4 + 64];
            float a8[8] = {aLo.x, aLo.y, aLo.z, aLo.w, aHi.x, aHi.y, aHi.z, aHi.w};
            float b8[8] = {bLo.x, bLo.y, bLo.z, bLo.w, bHi.x, bHi.y, bHi.z, bHi.w};
#pragma unroll
            for (int i = 0; i < 8; i++)
#pragma unroll
                for (int j = 0; j < 8; j++) acc[i][j] += a8[i] * b8[j];
        }
    }

    float* out = gp + (size_t)split * V * V;
#pragma unroll
    for (int i = 0; i < 8; i++) {
        int ra = ta + ((i < 4) ? (ty * 4 + i) : (64 + ty * 4 + i - 4));
        float4 lo = make_float4(acc[i][0], acc[i][1], acc[i][2], acc[i][3]);
        float4 hi = make_float4(acc[i][4], acc[i][5], acc[i][6], acc[i][7]);
        *(float4*)(out + (size_t)ra * V + tb + tx * 4) = lo;
        *(float4*)(out + (size_t)ra * V + tb + 64 + tx * 4) = hi;
    }
}

// ------------- reduce gpart -> S1, T1=sum g1 log g1, S2, T2=sum g2 log g2 ----
__global__ __launch_bounds__(256) void reduceg_k(const float* __restrict__ p,
                                                 const float* __restrict__ gp,
                                                 double* __restrict__ sc) {
    int base = blockIdx.x * 1024;     // 256 blocks x 1024 entries
    int t = threadIdx.x;
    double s1 = 0, t1 = 0, s2 = 0, t2 = 0;
#pragma unroll
    for (int e = 0; e < 4; e++) {
        int idx = base + e * 256 + t;
        int a = idx >> 9, b = idx & (V - 1);
        double g = 0;
#pragma unroll
        for (int s = 0; s < NSPLIT; s++) g += (double)gp[(size_t)s * V * V + idx];
        // subtract cross-sequence-boundary pairs (l = L-1 -> next seq l = 0)
        double cross = 0;
#pragma unroll
        for (int n = 0; n < 7; n++)
            cross += (double)p[(size_t)(n * L_SEQ + L_SEQ - 1) * V + a] *
                     (double)p[(size_t)((n + 1) * L_SEQ) * V + b];
        // subtract l = L-2 pairs to get bi_part
        double cc = 0;
#pragma unroll
        for (int n = 0; n < 8; n++)
            cc += (double)p[(size_t)(n * L_SEQ + L_SEQ - 2) * V + a] *
                  (double)p[(size_t)(n * L_SEQ + L_SEQ - 1) * V + b];
        double g1 = g - cross;
        double g2 = g1 - cc;
        s1 += g1; t1 += g1 * log(g1);
        s2 += g2; t2 += g2 * log(g2);
    }
#pragma unroll
    for (int o = 32; o; o >>= 1) {
        s1 += __shfl_xor(s1, o, 64);
        t1 += __shfl_xor(t1, o, 64);
        s2 += __shfl_xor(s2, o, 64);
        t2 += __shfl_xor(t2, o, 64);
    }
    if ((t & 63) == 0) {
        atomicAdd(&sc[0], s1);
        atomicAdd(&sc[1], t1);
        atomicAdd(&sc[2], s2);
        atomicAdd(&sc[3], t2);
    }
}

// ------------------- final: marginal entropy + combine -----------------------
__global__ __launch_bounds__(512) void final_k(const float* __restrict__ m,
                                               const double* __restrict__ sc,
                                               float* __restrict__ out) {
    int t = threadIdx.x;
    double mv = (double)m[t];
    double sm = mv;
    double tm = mv * log(mv);
#pragma unroll
    for (int o = 32; o; o >>= 1) {
        sm += __shfl_xor(sm, o, 64);
        tm += __shfl_xor(tm, o, 64);
    }
    __shared__ double red[2][8];
    if ((t & 63) == 0) { red[0][t >> 6] = sm; red[1][t >> 6] = tm; }
    __syncthreads();
    if (t == 0) {
        double Sm = 0, Tm = 0;
        for (int w = 0; w < 8; w++) { Sm += red[0][w]; Tm += red[1][w]; }
        double S1 = sc[0], T1 = sc[1], S2 = sc[2], T2 = sc[3];
        // bigram: H = -sum j log j, j = g/(S1+EPS)
        double D1 = S1 + EPS;
        double Hbi = (log(D1) * S1 - T1) / D1;
        double mlb = log((double)V * (double)V);
        double cbi = 1.0 - Hbi / (mlb + EPS);
        cbi = fmin(fmax(cbi, 0.0), 1.0);
        // trigram (factorized): t_abc = g2[a,b]*m[c]
        double S3 = S2 * Sm;
        double D3 = S3 + EPS;
        double Htri = (log(D3) * S3 - (Sm * T2 + S2 * Tm)) / D3;
        double mlt = log((double)V * (double)V * (double)V);
        double ctri = 1.0 - Htri / (mlt + EPS);
        ctri = fmin(fmax(ctri, 0.0), 1.0);
        double tot = 0.5 * cbi + 0.5 * ctri;
        if (!(tot == tot)) tot = 0.0;           // nan_to_num
        tot = fmin(fmax(tot, 0.0), 1.0);
        out[0] = (float)tot;
    }
}

extern "C" void kernel_launch(void* const* d_in, const int* in_sizes, int n_in,
                              void* d_out, int out_size, void* d_ws, size_t ws_size,
                              hipStream_t stream) {
    (void)in_sizes; (void)n_in; (void)out_size; (void)ws_size;
    const float* logits = (const float*)d_in[0];
    float* out = (float*)d_out;
    char* ws = (char*)d_ws;
    float* p = (float*)(ws + P_OFF);
    float* gp = (float*)(ws + GP_OFF);
    float* m = (float*)(ws + M_OFF);
    double* sc = (double*)(ws + SC_OFF);

    // zero the pad row of p, the marginal accumulator, and the 4 scalar accumulators
    (void)hipMemsetAsync(p + (size_t)NROWS * V, 0, V * sizeof(float), stream);
    (void)hipMemsetAsync(m, 0, V * sizeof(float) + 4 * sizeof(double), stream);

    softmax_k<<<NROWS, 64, 0, stream>>>(logits, p);
    colsum_k<<<256, 256, 0, stream>>>(p, m);
    gemm_k<<<16 * NSPLIT, 256, 0, stream>>>(p, gp);
    reduceg_k<<<256, 256, 0, stream>>>(p, gp, sc);
    final_k<<<1, 512, 0, stream>>>(m, sc, out);
}

// Round 3
// 184.846 us; speedup vs baseline: 1.3902x; 1.3902x over previous
//
#include <hip/hip_runtime.h>
#include <math.h>

#define L_SEQ 2048
#define V 512
#define NROWS 16384
#define LDT 16392          // pT row stride in elements (16384 data + 8 pad); LDT*2 = 32784 = 2049*16
#define NSPLIT 32
#define EPS 1e-10

typedef __bf16 bf16x8 __attribute__((ext_vector_type(8)));
typedef float f32x4 __attribute__((ext_vector_type(4)));

// ---- workspace layout (bytes) ----
// pT     : 512 x LDT bf16 (vocab-major transposed softmax, bf16-rounded)   16,785,408
// gp     : NSPLIT x 512 x 512 fp32 GEMM partials                           33,554,432
// rb     : 23 x 512 fp32 (bf16-rounded boundary rows for corrections)          47,104
// m      : 512 fp32 third-position marginal                                     2,048
// sc     : 4 doubles S1,T1,S2,T2                                                   32
#define PT_OFF  ((size_t)0)
#define GP_OFF  ((size_t)512 * LDT * 2)
#define RB_OFF  (GP_OFF + (size_t)NSPLIT * V * V * 4)
#define M_OFF   (RB_OFF + (size_t)23 * V * 4)
#define SC_OFF  (M_OFF + (size_t)V * 4)

#define GLDS16(g, l) __builtin_amdgcn_global_load_lds( \
    (const __attribute__((address_space(1))) unsigned int*)(g), \
    (__attribute__((address_space(3))) unsigned int*)(l), 16, 0, 0)

__device__ __forceinline__ unsigned short f2bf(float f) {
    unsigned u = __float_as_uint(f);
    unsigned r = (u + 0x7fffu + ((u >> 16) & 1u)) >> 16;   // RNE
    return (unsigned short)r;
}

// one wave (64 lanes) computes sanitize+softmax of a 512-row, bf16-rounded.
// lane covers elements [lane*4, lane*4+4) and [256+lane*4, ...+4).
__device__ __forceinline__ void softmax_row_bf16(const float* __restrict__ x,
                                                 int lane, unsigned short* out) {
    float4 va = *(const float4*)(x + lane * 4);
    float4 vb = *(const float4*)(x + 256 + lane * 4);
    float v[8] = {va.x, va.y, va.z, va.w, vb.x, vb.y, vb.z, vb.w};
#pragma unroll
    for (int i = 0; i < 8; i++) {
        float xi = v[i];
        if (isnan(xi)) xi = 0.0f;
        else if (isinf(xi)) xi = xi > 0.0f ? 80.0f : -80.0f;
        v[i] = xi;
    }
    float mx = v[0];
#pragma unroll
    for (int i = 1; i < 8; i++) mx = fmaxf(mx, v[i]);
#pragma unroll
    for (int o = 32; o; o >>= 1) mx = fmaxf(mx, __shfl_xor(mx, o, 64));
    float e[8];
    float s = 0.0f;
#pragma unroll
    for (int i = 0; i < 8; i++) { e[i] = expf(v[i] - mx); s += e[i]; }
#pragma unroll
    for (int o = 32; o; o >>= 1) s += __shfl_xor(s, o, 64);
    float inv = 1.0f / s;
#pragma unroll
    for (int i = 0; i < 8; i++) out[i] = f2bf(e[i] * inv);
}

// ------------- fused softmax + bf16 + transpose: 512 blocks x 32 rows -------
__global__ __launch_bounds__(256) void softmaxT_k(const float* __restrict__ in,
                                                  unsigned short* __restrict__ pT) {
    __shared__ __align__(16) unsigned short sm[32 * 512];
    int t = threadIdx.x;
    int w = t >> 6, lane = t & 63;
    int k0 = blockIdx.x * 32;
#pragma unroll
    for (int i = 0; i < 8; i++) {
        int rr = w * 8 + i;
        unsigned short o[8];
        softmax_row_bf16(in + (size_t)(k0 + rr) * V, lane, o);
        *(ushort4*)&sm[rr * 512 + lane * 4] = make_ushort4(o[0], o[1], o[2], o[3]);
        *(ushort4*)&sm[rr * 512 + 256 + lane * 4] = make_ushort4(o[4], o[5], o[6], o[7]);
    }
    __syncthreads();
    // transpose: thread t handles columns v0=2t, v0+1
    int v0 = 2 * t;
    unsigned u[32];
#pragma unroll
    for (int k = 0; k < 32; k++) u[k] = *(const unsigned*)&sm[k * 512 + v0];
    unsigned oA[16], oB[16];
#pragma unroll
    for (int i = 0; i < 16; i++) {
        unsigned e0 = u[2 * i], e1 = u[2 * i + 1];
        oA[i] = (e0 & 0xffffu) | (e1 << 16);
        oB[i] = (e0 >> 16) | (e1 & 0xffff0000u);
    }
    uint4* dA = (uint4*)(pT + (size_t)v0 * LDT + k0);
    uint4* dB = (uint4*)(pT + (size_t)(v0 + 1) * LDT + k0);
#pragma unroll
    for (int i = 0; i < 4; i++) {
        dA[i] = make_uint4(oA[4 * i], oA[4 * i + 1], oA[4 * i + 2], oA[4 * i + 3]);
        dB[i] = make_uint4(oB[4 * i], oB[4 * i + 1], oB[4 * i + 2], oB[4 * i + 3]);
    }
    if (blockIdx.x == 511) {   // zero the 8-element pad tail of every row
        *(uint4*)(pT + (size_t)v0 * LDT + 16384) = make_uint4(0, 0, 0, 0);
        *(uint4*)(pT + (size_t)(v0 + 1) * LDT + 16384) = make_uint4(0, 0, 0, 0);
    }
}

// ------------- boundary rows replay (identical math -> identical bf16) ------
__global__ __launch_bounds__(64) void rows_k(const float* __restrict__ in,
                                             float* __restrict__ rb) {
    int j = blockIdx.x, lane = threadIdx.x;
    int r = j < 8 ? j * L_SEQ + L_SEQ - 2
          : j < 16 ? (j - 8) * L_SEQ + L_SEQ - 1
          : (j - 15) * L_SEQ;
    unsigned short o[8];
    softmax_row_bf16(in + (size_t)r * V, lane, o);
#pragma unroll
    for (int i = 0; i < 4; i++)
        rb[j * V + lane * 4 + i] = __uint_as_float((unsigned)o[i] << 16);
#pragma unroll
    for (int i = 0; i < 4; i++)
        rb[j * V + 256 + lane * 4 + i] = __uint_as_float((unsigned)o[4 + i] << 16);
}

// ------------- marginal over rows with l>=2 (reads pT rows, coalesced) ------
__global__ __launch_bounds__(256) void colsum_k(const unsigned short* __restrict__ pT,
                                                float* __restrict__ m) {
    int c = blockIdx.x, t = threadIdx.x;
    const unsigned short* row = pT + (size_t)c * LDT;
    float s = 0.0f;
#pragma unroll
    for (int j = 0; j < 8; j++) {
        int g = t + 256 * j;                       // granule of 8 bf16, k = 8g..8g+7
        uint4 x = *(const uint4*)(row + g * 8);
        float partial = 0.0f;
        unsigned ww[4] = {x.x, x.y, x.z, x.w};
#pragma unroll
        for (int qq = 0; qq < 4; qq++) {
            partial += __uint_as_float(ww[qq] << 16);
            partial += __uint_as_float(ww[qq] & 0xffff0000u);
        }
        if ((g & 255) == 0)                        // k%2048 in {0,1}: exclude
            partial -= __uint_as_float(ww[0] << 16) + __uint_as_float(ww[0] & 0xffff0000u);
        s += partial;
    }
#pragma unroll
    for (int o = 32; o; o >>= 1) s += __shfl_xor(s, o, 64);
    __shared__ float red[4];
    if ((t & 63) == 0) red[t >> 6] = s;
    __syncthreads();
    if (t == 0) m[c] = red[0] + red[1] + red[2] + red[3];
}

// ------------- bf16 MFMA GEMM: gp[s] = P^T P(+1) over 512-deep K slices -----
// 512 blocks = 16 (128x128 tiles) x 32 K-splits; 256 threads = 4 waves.
// LDS: row-major 16B granules, slot = 4*r + q (q = k-quad 0..3), A and B 8 KB each.
// A staged via global_load_lds (16B); B staged via aligned load + 1-element
// funnel shift + ds_write_b128 (the k+1 offset is 2 bytes — unalignable).
__global__ __launch_bounds__(256) void gemm_k(const unsigned short* __restrict__ pT,
                                              float* __restrict__ gp) {
    __shared__ __align__(16) uint4 ldsA[512];
    __shared__ __align__(16) uint4 ldsB[512];
    int tile = blockIdx.x & 15, split = blockIdx.x >> 4;
    int ta = (tile >> 2) * 128, tb = (tile & 3) * 128;
    int t = threadIdx.x, w = t >> 6, lane = t & 63;
    int l15 = lane & 15, q = lane >> 4;
    int wa = (w & 1) * 64, wb = (w >> 1) * 64;
    int k0base = split * 512;

    f32x4 acc[4][4];
#pragma unroll
    for (int g = 0; g < 4; g++)
#pragma unroll
        for (int h = 0; h < 4; h++) acc[g][h] = (f32x4){0.f, 0.f, 0.f, 0.f};

    // staging assignment: wave w, lane -> granule slot 64w+lane and 256+64w+lane
    // slot s -> row r = s>>2 (within 128-row tile), quad = s&3
    int srow = 16 * w + (lane >> 2);
    int qoff = (lane & 3) * 8;
    const size_t rA1 = (size_t)(ta + srow) * LDT;
    const size_t rA2 = (size_t)(ta + 64 + srow) * LDT;
    const size_t rB1 = (size_t)(tb + srow) * LDT;
    const size_t rB2 = (size_t)(tb + 64 + srow) * LDT;

    for (int it = 0; it < 16; it++) {
        int kel = k0base + it * 32 + qoff;
        // B global loads (prev-iter compute overlaps these)
        const unsigned short* gb1 = pT + rB1 + kel;
        const unsigned short* gb2 = pT + rB2 + kel;
        uint4 x1 = *(const uint4*)gb1;
        unsigned y1 = *(const unsigned*)(gb1 + 8);
        uint4 x2 = *(const uint4*)gb2;
        unsigned y2 = *(const unsigned*)(gb2 + 8);
        __syncthreads();                 // prev frag reads done before overwrite
        GLDS16(pT + rA1 + kel, &ldsA[64 * w]);
        GLDS16(pT + rA2 + kel, &ldsA[256 + 64 * w]);
        uint4 s1, s2;
        s1.x = (x1.x >> 16) | (x1.y << 16);
        s1.y = (x1.y >> 16) | (x1.z << 16);
        s1.z = (x1.z >> 16) | (x1.w << 16);
        s1.w = (x1.w >> 16) | (y1 << 16);
        s2.x = (x2.x >> 16) | (x2.y << 16);
        s2.y = (x2.y >> 16) | (x2.z << 16);
        s2.z = (x2.z >> 16) | (x2.w << 16);
        s2.w = (x2.w >> 16) | (y2 << 16);
        ldsB[64 * w + lane] = s1;
        ldsB[256 + 64 * w + lane] = s2;
        __syncthreads();                 // staging visible (drains vmcnt+lgkm)
        bf16x8 af[4], bv[4];
#pragma unroll
        for (int g = 0; g < 4; g++)
            af[g] = __builtin_bit_cast(bf16x8, ldsA[4 * (wa + g * 16 + l15) + q]);
#pragma unroll
        for (int h = 0; h < 4; h++)
            bv[h] = __builtin_bit_cast(bf16x8, ldsB[4 * (wb + h * 16 + l15) + q]);
#pragma unroll
        for (int g = 0; g < 4; g++)
#pragma unroll
            for (int h = 0; h < 4; h++)
                acc[g][h] = __builtin_amdgcn_mfma_f32_16x16x32_bf16(af[g], bv[h], acc[g][h], 0, 0, 0);
    }

    // C/D layout: col = lane&15, row = (lane>>4)*4 + reg  [m89/m91]
    float* og = gp + (size_t)split * V * V;
#pragma unroll
    for (int g = 0; g < 4; g++) {
        int a = ta + wa + g * 16 + q * 4;
#pragma unroll
        for (int h = 0; h < 4; h++) {
            int b = tb + wb + h * 16 + l15;
#pragma unroll
            for (int r = 0; r < 4; r++)
                og[(size_t)(a + r) * V + b] = acc[g][h][r];
        }
    }
}

// ------------- reduce gp + boundary corrections -> S1,T1,S2,T2 --------------
__global__ __launch_bounds__(256) void reduceg_k(const float* __restrict__ gp,
                                                 const float* __restrict__ rb,
                                                 double* __restrict__ sc) {
    int base = blockIdx.x * 1024;
    int t = threadIdx.x;
    double s1 = 0, t1 = 0, s2 = 0, t2 = 0;
#pragma unroll
    for (int e = 0; e < 4; e++) {
        int idx = base + e * 256 + t;
        int a = idx >> 9, b = idx & (V - 1);
        double g = 0;
#pragma unroll
        for (int s = 0; s < NSPLIT; s++) g += (double)gp[(size_t)s * V * V + idx];
        double cross = 0, cc = 0;
#pragma unroll
        for (int n = 0; n < 7; n++)
            cross += (double)rb[(8 + n) * V + a] * (double)rb[(16 + n) * V + b];
#pragma unroll
        for (int n = 0; n < 8; n++)
            cc += (double)rb[n * V + a] * (double)rb[(8 + n) * V + b];
        double g1 = g - cross;       // bigram_joint entry
        double g2 = g1 - cc;         // bi_part entry
        s1 += g1; t1 += g1 * log(g1);
        s2 += g2; t2 += g2 * log(g2);
    }
#pragma unroll
    for (int o = 32; o; o >>= 1) {
        s1 += __shfl_xor(s1, o, 64);
        t1 += __shfl_xor(t1, o, 64);
        s2 += __shfl_xor(s2, o, 64);
        t2 += __shfl_xor(t2, o, 64);
    }
    if ((t & 63) == 0) {
        atomicAdd(&sc[0], s1);
        atomicAdd(&sc[1], t1);
        atomicAdd(&sc[2], s2);
        atomicAdd(&sc[3], t2);
    }
}

// ------------------- final: marginal entropy + combine -----------------------
__global__ __launch_bounds__(512) void final_k(const float* __restrict__ m,
                                               const double* __restrict__ sc,
                                               float* __restrict__ out) {
    int t = threadIdx.x;
    double mv = (double)m[t];
    double sm = mv;
    double tm = mv * log(mv);
#pragma unroll
    for (int o = 32; o; o >>= 1) {
        sm += __shfl_xor(sm, o, 64);
        tm += __shfl_xor(tm, o, 64);
    }
    __shared__ double red[2][8];
    if ((t & 63) == 0) { red[0][t >> 6] = sm; red[1][t >> 6] = tm; }
    __syncthreads();
    if (t == 0) {
        double Sm = 0, Tm = 0;
        for (int w = 0; w < 8; w++) { Sm += red[0][w]; Tm += red[1][w]; }
        double S1 = sc[0], T1 = sc[1], S2 = sc[2], T2 = sc[3];
        double D1 = S1 + EPS;
        double Hbi = (log(D1) * S1 - T1) / D1;
        double mlb = log((double)V * (double)V);
        double cbi = 1.0 - Hbi / (mlb + EPS);
        cbi = fmin(fmax(cbi, 0.0), 1.0);
        double S3 = S2 * Sm;
        double D3 = S3 + EPS;
        double Htri = (log(D3) * S3 - (Sm * T2 + S2 * Tm)) / D3;
        double mlt = log((double)V * (double)V * (double)V);
        double ctri = 1.0 - Htri / (mlt + EPS);
        ctri = fmin(fmax(ctri, 0.0), 1.0);
        double tot = 0.5 * cbi + 0.5 * ctri;
        if (!(tot == tot)) tot = 0.0;
        tot = fmin(fmax(tot, 0.0), 1.0);
        out[0] = (float)tot;
    }
}

extern "C" void kernel_launch(void* const* d_in, const int* in_sizes, int n_in,
                              void* d_out, int out_size, void* d_ws, size_t ws_size,
                              hipStream_t stream) {
    (void)in_sizes; (void)n_in; (void)out_size; (void)ws_size;
    const float* logits = (const float*)d_in[0];
    float* out = (float*)d_out;
    char* ws = (char*)d_ws;
    unsigned short* pT = (unsigned short*)(ws + PT_OFF);
    float* gp = (float*)(ws + GP_OFF);
    float* rb = (float*)(ws + RB_OFF);
    float* m = (float*)(ws + M_OFF);
    double* sc = (double*)(ws + SC_OFF);

    (void)hipMemsetAsync(sc, 0, 4 * sizeof(double), stream);
    softmaxT_k<<<512, 256, 0, stream>>>(logits, pT);
    rows_k<<<23, 64, 0, stream>>>(logits, rb);
    colsum_k<<<512, 256, 0, stream>>>(pT, m);
    gemm_k<<<512, 256, 0, stream>>>(pT, gp);
    reduceg_k<<<256, 256, 0, stream>>>(gp, rb, sc);
    final_k<<<1, 512, 0, stream>>>(m, sc, out);
}

// Round 4
// 131.577 us; speedup vs baseline: 1.9530x; 1.4049x over previous
//
#include <hip/hip_runtime.h>
#include <math.h>

#define L_SEQ 2048
#define V 512
#define NROWS 16384
#define LDT 16392          // pT row stride in elements (16384 data + 8 pad); LDT*2 = 32784 = 2049*16
#define NSPLIT 32
#define EPS 1e-10

typedef __bf16 bf16x8 __attribute__((ext_vector_type(8)));
typedef float f32x4 __attribute__((ext_vector_type(4)));

// ---- workspace layout (bytes) ----
// pT     : 512 x LDT bf16 (vocab-major transposed softmax, bf16-rounded)   16,785,408
// gp     : NSPLIT x 512 x 512 fp32 GEMM partials                           33,554,432
// rb     : 23 x 512 fp32 (bf16-rounded boundary rows for corrections)          47,104
// m      : 512 fp32 third-position marginal                                     2,048
// pc     : 1024 x 4 doubles (per-block partials S1,T1,S2,T2)                   32,768
#define PT_OFF  ((size_t)0)
#define GP_OFF  ((size_t)512 * LDT * 2)
#define RB_OFF  (GP_OFF + (size_t)NSPLIT * V * V * 4)
#define M_OFF   (RB_OFF + (size_t)23 * V * 4)
#define PC_OFF  (M_OFF + (size_t)V * 4)

#define GLDS16(g, l) __builtin_amdgcn_global_load_lds( \
    (const __attribute__((address_space(1))) unsigned int*)(g), \
    (__attribute__((address_space(3))) unsigned int*)(l), 16, 0, 0)

__device__ __forceinline__ unsigned short f2bf(float f) {
    unsigned u = __float_as_uint(f);
    unsigned r = (u + 0x7fffu + ((u >> 16) & 1u)) >> 16;   // RNE
    return (unsigned short)r;
}

// one wave (64 lanes) computes sanitize+softmax of a 512-row, bf16-rounded.
// lane covers elements [lane*4, lane*4+4) and [256+lane*4, ...+4).
__device__ __forceinline__ void softmax_row_bf16(const float* __restrict__ x,
                                                 int lane, unsigned short* out) {
    float4 va = *(const float4*)(x + lane * 4);
    float4 vb = *(const float4*)(x + 256 + lane * 4);
    float v[8] = {va.x, va.y, va.z, va.w, vb.x, vb.y, vb.z, vb.w};
#pragma unroll
    for (int i = 0; i < 8; i++) {
        float xi = v[i];
        if (isnan(xi)) xi = 0.0f;
        else if (isinf(xi)) xi = xi > 0.0f ? 80.0f : -80.0f;
        v[i] = xi;
    }
    float mx = v[0];
#pragma unroll
    for (int i = 1; i < 8; i++) mx = fmaxf(mx, v[i]);
#pragma unroll
    for (int o = 32; o; o >>= 1) mx = fmaxf(mx, __shfl_xor(mx, o, 64));
    float e[8];
    float s = 0.0f;
#pragma unroll
    for (int i = 0; i < 8; i++) { e[i] = expf(v[i] - mx); s += e[i]; }
#pragma unroll
    for (int o = 32; o; o >>= 1) s += __shfl_xor(s, o, 64);
    float inv = 1.0f / s;
#pragma unroll
    for (int i = 0; i < 8; i++) out[i] = f2bf(e[i] * inv);
}

// ------------- fused softmax + bf16 + transpose: 512 blocks x 32 rows -------
__global__ __launch_bounds__(256) void softmaxT_k(const float* __restrict__ in,
                                                  unsigned short* __restrict__ pT) {
    __shared__ __align__(16) unsigned short sm[32 * 512];
    int t = threadIdx.x;
    int w = t >> 6, lane = t & 63;
    int k0 = blockIdx.x * 32;
#pragma unroll
    for (int i = 0; i < 8; i++) {
        int rr = w * 8 + i;
        unsigned short o[8];
        softmax_row_bf16(in + (size_t)(k0 + rr) * V, lane, o);
        *(ushort4*)&sm[rr * 512 + lane * 4] = make_ushort4(o[0], o[1], o[2], o[3]);
        *(ushort4*)&sm[rr * 512 + 256 + lane * 4] = make_ushort4(o[4], o[5], o[6], o[7]);
    }
    __syncthreads();
    // transpose: thread t handles columns v0=2t, v0+1
    int v0 = 2 * t;
    unsigned u[32];
#pragma unroll
    for (int k = 0; k < 32; k++) u[k] = *(const unsigned*)&sm[k * 512 + v0];
    unsigned oA[16], oB[16];
#pragma unroll
    for (int i = 0; i < 16; i++) {
        unsigned e0 = u[2 * i], e1 = u[2 * i + 1];
        oA[i] = (e0 & 0xffffu) | (e1 << 16);
        oB[i] = (e0 >> 16) | (e1 & 0xffff0000u);
    }
    uint4* dA = (uint4*)(pT + (size_t)v0 * LDT + k0);
    uint4* dB = (uint4*)(pT + (size_t)(v0 + 1) * LDT + k0);
#pragma unroll
    for (int i = 0; i < 4; i++) {
        dA[i] = make_uint4(oA[4 * i], oA[4 * i + 1], oA[4 * i + 2], oA[4 * i + 3]);
        dB[i] = make_uint4(oB[4 * i], oB[4 * i + 1], oB[4 * i + 2], oB[4 * i + 3]);
    }
    if (blockIdx.x == 511) {   // zero the 8-element pad tail of every row
        *(uint4*)(pT + (size_t)v0 * LDT + 16384) = make_uint4(0, 0, 0, 0);
        *(uint4*)(pT + (size_t)(v0 + 1) * LDT + 16384) = make_uint4(0, 0, 0, 0);
    }
}

// ------------- boundary rows replay (identical math -> identical bf16) ------
__global__ __launch_bounds__(64) void rows_k(const float* __restrict__ in,
                                             float* __restrict__ rb) {
    int j = blockIdx.x, lane = threadIdx.x;
    int r = j < 8 ? j * L_SEQ + L_SEQ - 2
          : j < 16 ? (j - 8) * L_SEQ + L_SEQ - 1
          : (j - 15) * L_SEQ;
    unsigned short o[8];
    softmax_row_bf16(in + (size_t)r * V, lane, o);
#pragma unroll
    for (int i = 0; i < 4; i++)
        rb[j * V + lane * 4 + i] = __uint_as_float((unsigned)o[i] << 16);
#pragma unroll
    for (int i = 0; i < 4; i++)
        rb[j * V + 256 + lane * 4 + i] = __uint_as_float((unsigned)o[4 + i] << 16);
}

// ------------- marginal over rows with l>=2 (reads pT rows, coalesced) ------
__global__ __launch_bounds__(256) void colsum_k(const unsigned short* __restrict__ pT,
                                                float* __restrict__ m) {
    int c = blockIdx.x, t = threadIdx.x;
    const unsigned short* row = pT + (size_t)c * LDT;
    float s = 0.0f;
#pragma unroll
    for (int j = 0; j < 8; j++) {
        int g = t + 256 * j;                       // granule of 8 bf16, k = 8g..8g+7
        uint4 x = *(const uint4*)(row + g * 8);
        float partial = 0.0f;
        unsigned ww[4] = {x.x, x.y, x.z, x.w};
#pragma unroll
        for (int qq = 0; qq < 4; qq++) {
            partial += __uint_as_float(ww[qq] << 16);
            partial += __uint_as_float(ww[qq] & 0xffff0000u);
        }
        if ((g & 255) == 0)                        // k%2048 in {0,1}: exclude
            partial -= __uint_as_float(ww[0] << 16) + __uint_as_float(ww[0] & 0xffff0000u);
        s += partial;
    }
#pragma unroll
    for (int o = 32; o; o >>= 1) s += __shfl_xor(s, o, 64);
    __shared__ float red[4];
    if ((t & 63) == 0) red[t >> 6] = s;
    __syncthreads();
    if (t == 0) m[c] = red[0] + red[1] + red[2] + red[3];
}

// ------------- bf16 MFMA GEMM: gp[s] = P^T P(+1) over 512-deep K slices -----
__global__ __launch_bounds__(256) void gemm_k(const unsigned short* __restrict__ pT,
                                              float* __restrict__ gp) {
    __shared__ __align__(16) uint4 ldsA[512];
    __shared__ __align__(16) uint4 ldsB[512];
    int tile = blockIdx.x & 15, split = blockIdx.x >> 4;
    int ta = (tile >> 2) * 128, tb = (tile & 3) * 128;
    int t = threadIdx.x, w = t >> 6, lane = t & 63;
    int l15 = lane & 15, q = lane >> 4;
    int wa = (w & 1) * 64, wb = (w >> 1) * 64;
    int k0base = split * 512;

    f32x4 acc[4][4];
#pragma unroll
    for (int g = 0; g < 4; g++)
#pragma unroll
        for (int h = 0; h < 4; h++) acc[g][h] = (f32x4){0.f, 0.f, 0.f, 0.f};

    int srow = 16 * w + (lane >> 2);
    int qoff = (lane & 3) * 8;
    const size_t rA1 = (size_t)(ta + srow) * LDT;
    const size_t rA2 = (size_t)(ta + 64 + srow) * LDT;
    const size_t rB1 = (size_t)(tb + srow) * LDT;
    const size_t rB2 = (size_t)(tb + 64 + srow) * LDT;

    for (int it = 0; it < 16; it++) {
        int kel = k0base + it * 32 + qoff;
        const unsigned short* gb1 = pT + rB1 + kel;
        const unsigned short* gb2 = pT + rB2 + kel;
        uint4 x1 = *(const uint4*)gb1;
        unsigned y1 = *(const unsigned*)(gb1 + 8);
        uint4 x2 = *(const uint4*)gb2;
        unsigned y2 = *(const unsigned*)(gb2 + 8);
        __syncthreads();                 // prev frag reads done before overwrite
        GLDS16(pT + rA1 + kel, &ldsA[64 * w]);
        GLDS16(pT + rA2 + kel, &ldsA[256 + 64 * w]);
        uint4 s1, s2;
        s1.x = (x1.x >> 16) | (x1.y << 16);
        s1.y = (x1.y >> 16) | (x1.z << 16);
        s1.z = (x1.z >> 16) | (x1.w << 16);
        s1.w = (x1.w >> 16) | (y1 << 16);
        s2.x = (x2.x >> 16) | (x2.y << 16);
        s2.y = (x2.y >> 16) | (x2.z << 16);
        s2.z = (x2.z >> 16) | (x2.w << 16);
        s2.w = (x2.w >> 16) | (y2 << 16);
        ldsB[64 * w + lane] = s1;
        ldsB[256 + 64 * w + lane] = s2;
        __syncthreads();                 // staging visible (drains vmcnt+lgkm)
        bf16x8 af[4], bv[4];
#pragma unroll
        for (int g = 0; g < 4; g++)
            af[g] = __builtin_bit_cast(bf16x8, ldsA[4 * (wa + g * 16 + l15) + q]);
#pragma unroll
        for (int h = 0; h < 4; h++)
            bv[h] = __builtin_bit_cast(bf16x8, ldsB[4 * (wb + h * 16 + l15) + q]);
#pragma unroll
        for (int g = 0; g < 4; g++)
#pragma unroll
            for (int h = 0; h < 4; h++)
                acc[g][h] = __builtin_amdgcn_mfma_f32_16x16x32_bf16(af[g], bv[h], acc[g][h], 0, 0, 0);
    }

    // C/D layout: col = lane&15, row = (lane>>4)*4 + reg  [m89/m91]
    float* og = gp + (size_t)split * V * V;
#pragma unroll
    for (int g = 0; g < 4; g++) {
        int a = ta + wa + g * 16 + q * 4;
#pragma unroll
        for (int h = 0; h < 4; h++) {
            int b = tb + wb + h * 16 + l15;
#pragma unroll
            for (int r = 0; r < 4; r++)
                og[(size_t)(a + r) * V + b] = acc[g][h][r];
        }
    }
}

// ------- reduce gp + boundary corrections -> per-block S1,T1,S2,T2 ----------
// 1024 blocks x 256 threads, 1 entry/thread. No atomics: partials to pc[].
__global__ __launch_bounds__(256) void reduceg_k(const float* __restrict__ gp,
                                                 const float* __restrict__ rb,
                                                 double* __restrict__ pc) {
    int t = threadIdx.x;
    int idx = blockIdx.x * 256 + t;
    int a = idx >> 9, b = idx & (V - 1);
    // sum 32 split partials in double, 4-way interleaved to break the chain
    double ga = 0, gb2 = 0, gc = 0, gd = 0;
#pragma unroll
    for (int s = 0; s < NSPLIT; s += 4) {
        ga += (double)gp[(size_t)(s + 0) * V * V + idx];
        gb2 += (double)gp[(size_t)(s + 1) * V * V + idx];
        gc += (double)gp[(size_t)(s + 2) * V * V + idx];
        gd += (double)gp[(size_t)(s + 3) * V * V + idx];
    }
    double g = (ga + gb2) + (gc + gd);
    // corrections in fp32 (they are ~5e-4 of g; fp32 noise ~1e-11 absolute)
    float cross = 0.f, cc = 0.f;
#pragma unroll
    for (int n = 0; n < 7; n++)
        cross = fmaf(rb[(8 + n) * V + a], rb[(16 + n) * V + b], cross);
#pragma unroll
    for (int n = 0; n < 8; n++)
        cc = fmaf(rb[n * V + a], rb[(8 + n) * V + b], cc);
    double g1 = g - (double)cross;     // bigram_joint entry
    double g2 = g1 - (double)cc;       // bi_part entry
    double s1 = g1, t1 = g1 * (double)logf((float)g1);
    double s2 = g2, t2 = g2 * (double)logf((float)g2);
#pragma unroll
    for (int o = 32; o; o >>= 1) {
        s1 += __shfl_xor(s1, o, 64);
        t1 += __shfl_xor(t1, o, 64);
        s2 += __shfl_xor(s2, o, 64);
        t2 += __shfl_xor(t2, o, 64);
    }
    __shared__ double red[4][4];
    if ((t & 63) == 0) {
        int w = t >> 6;
        red[w][0] = s1; red[w][1] = t1; red[w][2] = s2; red[w][3] = t2;
    }
    __syncthreads();
    if (t == 0) {
        double* o = pc + (size_t)blockIdx.x * 4;
        o[0] = red[0][0] + red[1][0] + red[2][0] + red[3][0];
        o[1] = red[0][1] + red[1][1] + red[2][1] + red[3][1];
        o[2] = red[0][2] + red[1][2] + red[2][2] + red[3][2];
        o[3] = red[0][3] + red[1][3] + red[2][3] + red[3][3];
    }
}

// ------------------- final: partial sums + marginal entropy + combine --------
__global__ __launch_bounds__(512) void final_k(const float* __restrict__ m,
                                               const double* __restrict__ pc,
                                               float* __restrict__ out) {
    int t = threadIdx.x;
    double s1 = 0, t1 = 0, s2 = 0, t2 = 0;
#pragma unroll
    for (int j = 0; j < 2; j++) {
        const double* q = pc + (size_t)(t + 512 * j) * 4;
        s1 += q[0]; t1 += q[1]; s2 += q[2]; t2 += q[3];
    }
    double mv = (double)m[t];
    double sm = mv;
    double tm = mv * log(mv);
#pragma unroll
    for (int o = 32; o; o >>= 1) {
        sm += __shfl_xor(sm, o, 64);
        tm += __shfl_xor(tm, o, 64);
        s1 += __shfl_xor(s1, o, 64);
        t1 += __shfl_xor(t1, o, 64);
        s2 += __shfl_xor(s2, o, 64);
        t2 += __shfl_xor(t2, o, 64);
    }
    __shared__ double red[6][8];
    if ((t & 63) == 0) {
        int w = t >> 6;
        red[0][w] = sm; red[1][w] = tm;
        red[2][w] = s1; red[3][w] = t1;
        red[4][w] = s2; red[5][w] = t2;
    }
    __syncthreads();
    if (t == 0) {
        double acc[6];
        for (int i = 0; i < 6; i++) {
            acc[i] = 0;
            for (int w = 0; w < 8; w++) acc[i] += red[i][w];
        }
        double Sm = acc[0], Tm = acc[1];
        double S1 = acc[2], T1 = acc[3], S2 = acc[4], T2 = acc[5];
        double D1 = S1 + EPS;
        double Hbi = (log(D1) * S1 - T1) / D1;
        double mlb = log((double)V * (double)V);
        double cbi = 1.0 - Hbi / (mlb + EPS);
        cbi = fmin(fmax(cbi, 0.0), 1.0);
        double S3 = S2 * Sm;
        double D3 = S3 + EPS;
        double Htri = (log(D3) * S3 - (Sm * T2 + S2 * Tm)) / D3;
        double mlt = log((double)V * (double)V * (double)V);
        double ctri = 1.0 - Htri / (mlt + EPS);
        ctri = fmin(fmax(ctri, 0.0), 1.0);
        double tot = 0.5 * cbi + 0.5 * ctri;
        if (!(tot == tot)) tot = 0.0;
        tot = fmin(fmax(tot, 0.0), 1.0);
        out[0] = (float)tot;
    }
}

extern "C" void kernel_launch(void* const* d_in, const int* in_sizes, int n_in,
                              void* d_out, int out_size, void* d_ws, size_t ws_size,
                              hipStream_t stream) {
    (void)in_sizes; (void)n_in; (void)out_size; (void)ws_size;
    const float* logits = (const float*)d_in[0];
    float* out = (float*)d_out;
    char* ws = (char*)d_ws;
    unsigned short* pT = (unsigned short*)(ws + PT_OFF);
    float* gp = (float*)(ws + GP_OFF);
    float* rb = (float*)(ws + RB_OFF);
    float* m = (float*)(ws + M_OFF);
    double* pc = (double*)(ws + PC_OFF);

    softmaxT_k<<<512, 256, 0, stream>>>(logits, pT);
    rows_k<<<23, 64, 0, stream>>>(logits, rb);
    colsum_k<<<512, 256, 0, stream>>>(pT, m);
    gemm_k<<<512, 256, 0, stream>>>(pT, gp);
    reduceg_k<<<1024, 256, 0, stream>>>(gp, rb, pc);
    final_k<<<1, 512, 0, stream>>>(m, pc, out);
}